// Round 9
// baseline (927.801 us; speedup 1.0000x reference)
//
#include <hip/hip_runtime.h>
#include <stdint.h>
#include <stdio.h>

#define Td 4096
#define Hd 1024
#define Ed 8
#define Fd 4096
#define ROWS_CAP 9216   // 8192 pairs + 8*128 alignment slack

typedef unsigned int u32;
typedef unsigned short u16;
typedef float f32x4 __attribute__((ext_vector_type(4)));
typedef float f32x2 __attribute__((ext_vector_type(2)));
typedef __bf16 bf16x8 __attribute__((ext_vector_type(8)));
typedef u16 u16x8 __attribute__((ext_vector_type(8)));
typedef u16 u16x4 __attribute__((ext_vector_type(4)));
typedef u32 u32x4 __attribute__((ext_vector_type(4)));

#define ASG __attribute__((address_space(1)))
#define ASL __attribute__((address_space(3)))

__device__ __forceinline__ void gll16(const void* g, void* l) {
  __builtin_amdgcn_global_load_lds((const ASG u32*)g, (ASL u32*)l, 16, 0, 0);
}

__device__ __forceinline__ u16 f2bf(float f) {
  u32 u = __float_as_uint(f);
  u = u + 0x7fffu + ((u >> 16) & 1u);
  return (u16)(u >> 16);
}

// ---------------- gate: logits (f64 accum), top-2, softmax*alpha, LN stats ----
__global__ __launch_bounds__(256) void k_gate(const float* __restrict__ x,
    const float* __restrict__ Wg, const float* __restrict__ alpha,
    float* __restrict__ mu, float* __restrict__ rstd,
    int* __restrict__ tok_e, float* __restrict__ tok_w)
{
  const int t = blockIdx.x, tid = threadIdx.x;
  const f32x4 xv = *(const f32x4*)(x + (size_t)t*Hd + tid*4);
  float s1 = 0.f, s2 = 0.f;
  double lg[8];
#pragma unroll
  for (int e=0;e<8;e++) lg[e]=0.0;
#pragma unroll
  for (int i=0;i<4;i++){
    const float xi = xv[i];
    s1 += xi; s2 += xi*xi;
    const f32x4 wa = *(const f32x4*)(Wg + (size_t)(tid*4+i)*Ed);
    const f32x4 wb = *(const f32x4*)(Wg + (size_t)(tid*4+i)*Ed + 4);
    lg[0] += (double)xi*(double)wa[0]; lg[1] += (double)xi*(double)wa[1];
    lg[2] += (double)xi*(double)wa[2]; lg[3] += (double)xi*(double)wa[3];
    lg[4] += (double)xi*(double)wb[0]; lg[5] += (double)xi*(double)wb[1];
    lg[6] += (double)xi*(double)wb[2]; lg[7] += (double)xi*(double)wb[3];
  }
#pragma unroll
  for (int off=32; off>0; off>>=1){
    s1 += __shfl_down(s1, off);
    s2 += __shfl_down(s2, off);
#pragma unroll
    for (int e=0;e<8;e++) lg[e] += __shfl_down(lg[e], off);
  }
  __shared__ double sl[4][8];
  __shared__ float sa[4], sb[4];
  const int w = tid>>6, lane = tid&63;
  if (lane==0){
#pragma unroll
    for (int e=0;e<8;e++) sl[w][e]=lg[e];
    sa[w]=s1; sb[w]=s2;
  }
  __syncthreads();
  if (tid==0){
    float S1=0.f,S2=0.f; double L[8];
#pragma unroll
    for (int e=0;e<8;e++) L[e]=0.0;
#pragma unroll
    for (int i=0;i<4;i++){
      S1+=sa[i]; S2+=sb[i];
#pragma unroll
      for (int e=0;e<8;e++) L[e]+=sl[i][e];
    }
    const float mean = S1 * (1.f/Hd);
    float var = S2 * (1.f/Hd) - mean*mean;
    if (var < 0.f) var = 0.f;
    mu[t]=mean; rstd[t]=rsqrtf(var + 1e-5f);
    float l[8];
#pragma unroll
    for (int e=0;e<8;e++) l[e]=(float)L[e];
    int e0=0;
#pragma unroll
    for (int e=1;e<8;e++) if (l[e]>l[e0]) e0=e;
    int e1=-1;
#pragma unroll
    for (int e=0;e<8;e++) if (e!=e0 && (e1<0 || l[e]>l[e1])) e1=e;
    const float p = __expf(l[e1]-l[e0]);     // <= 1
    const float inv = 1.f/(1.f+p);
    tok_e[2*t]=e0; tok_e[2*t+1]=e1;
    tok_w[2*t]   = inv   * alpha[e0];
    tok_w[2*t+1] = p*inv * alpha[e1];
  }
}

// ---------------- parallel deterministic routing -----------------------------
__global__ __launch_bounds__(256) void k_hist(const int* __restrict__ tok_e,
                                              int* __restrict__ cnt)
{
  __shared__ int c[8];
  const int tid = threadIdx.x, ch = blockIdx.x;
  if (tid < 8) c[tid] = 0;
  __syncthreads();
  const int t = ch*256 + tid;
  atomicAdd(&c[tok_e[2*t]], 1);
  atomicAdd(&c[tok_e[2*t+1]], 1);
  __syncthreads();
  if (tid < 8) cnt[ch*8 + tid] = c[tid];
}

__global__ __launch_bounds__(64) void k_scan(const int* __restrict__ cnt,
                                             int* __restrict__ meta,
                                             int* __restrict__ base)
{
  if (threadIdx.x != 0) return;
  int s = 0;
  for (int e=0;e<8;e++){
    meta[e] = s;
    int run = s;
    for (int ch=0; ch<Td/256; ++ch){
      base[ch*8+e] = run;
      run += cnt[ch*8+e];
    }
    s += (run - s + 127) & ~127;     // 128-row alignment for 128-tile GEMM
  }
  meta[8] = s;
}

__global__ __launch_bounds__(256) void k_scatter(const int* __restrict__ tok_e,
    const float* __restrict__ tok_w, const int* __restrict__ base,
    int* __restrict__ gtok, float* __restrict__ gw)
{
  __shared__ int wsum[4];
  const int tid = threadIdx.x, ch = blockIdx.x, w = tid>>6, lane = tid&63;
  const int t = ch*256 + tid;
  const int e0 = tok_e[2*t], e1 = tok_e[2*t+1];
  for (int e=0;e<8;e++){
    const bool fa = (e0 == e);
    const bool f  = fa || (e1 == e);
    const unsigned long long bal = __ballot(f);
    if (lane==0) wsum[w] = __popcll(bal);
    __syncthreads();
    int pre=0;
#pragma unroll
    for (int i=0;i<4;i++){ if (i<w) pre += wsum[i]; }
    if (f){
      const int pos = base[ch*8+e] + pre + __popcll(bal & ((1ull<<lane)-1ull));
      gtok[pos] = t;
      gw[pos]   = tok_w[2*t + (fa?0:1)];
    }
    __syncthreads();
  }
}

// ---------------- gather + LayerNorm -> bf16 Xg (chunk-swizzled) -------------
__global__ __launch_bounds__(256) void k_gather(const float* __restrict__ x,
    const float* __restrict__ lnw, const float* __restrict__ lnb,
    const float* __restrict__ mu, const float* __restrict__ rstd,
    const int* __restrict__ meta, const int* __restrict__ gtok,
    u16* __restrict__ Xg)
{
  const int r = blockIdx.x, tid = threadIdx.x;
  __shared__ int ps[9];
  if (tid < 9) ps[tid] = meta[tid];
  __syncthreads();
  if (r >= ps[8]) return;
  int e = 0;
#pragma unroll
  for (int i=1;i<8;i++) if (r >= ps[i]) e = i;
  const int k0 = tid*4;
  const int c  = k0 >> 3;
  const int cs = (c & ~7) | ((c ^ r) & 7);       // XOR-swizzle 16B chunks in 128B blocks
  u16* dst = Xg + (size_t)r*Hd + cs*8 + (k0 & 7);
  const int t = gtok[r];
  u16x4 o;
  if (t < 0){
    o[0]=0;o[1]=0;o[2]=0;o[3]=0;
  } else {
    const float m = mu[t], s = rstd[t];
    const f32x4 xv = *(const f32x4*)(x   + (size_t)t*Hd + k0);
    const f32x4 wv = *(const f32x4*)(lnw + (size_t)e*Hd + k0);
    const f32x4 bv = *(const f32x4*)(lnb + (size_t)e*Hd + k0);
#pragma unroll
    for (int i=0;i<4;i++) o[i] = f2bf((xv[i]-m)*s*wv[i] + bv[i]);
  }
  *(u16x4*)dst = o;
}

// ---------------- weight prepass: [e][K][N] f32 -> [e][N][K] bf16, swizzled --
template<int K, int N>
__global__ __launch_bounds__(256) void k_wt(const float* __restrict__ W,
                                            u16* __restrict__ Wt)
{
  const int e = blockIdx.z, kb = blockIdx.x*64, nb = blockIdx.y*64;
  __shared__ u16 T[64*66];
  const int tid = threadIdx.x;
#pragma unroll
  for (int j=0;j<8;j++){
    const int idx = j*256 + tid;          // 2048 f32x2 pairs
    const int k = idx >> 5;               // 0..63
    const int n = (idx & 31) << 1;        // 0..62 even
    const f32x2 v = *(const f32x2*)(W + ((size_t)e*K + kb + k)*N + nb + n);
    T[n*66 + k]     = f2bf(v[0]);
    T[(n+1)*66 + k] = f2bf(v[1]);
  }
  __syncthreads();
  const int nl = tid >> 2;
  const int gn = nb + nl;
  u16* dstrow = Wt + ((size_t)e*N + gn)*K;
#pragma unroll
  for (int cc=0; cc<2; ++cc){
    const int c = ((tid & 3) << 1) + cc;  // local chunk 0..7
    u32x4 v;
#pragma unroll
    for (int i=0;i<4;i++) v[i] = *(const u32*)&T[nl*66 + c*8 + i*2];
    const int cabs = (kb >> 3) + c;
    const int cs = (cabs & ~7) | ((cabs ^ gn) & 7);
    *(u32x4*)(dstrow + cs*8) = v;
  }
}

// ---------------- grouped GEMM: 128x128, BK=64, 4 waves, REG-STAGED ----------
// Round-6 structure (best measured: 177us/GEMM) + two additions:
//  (1) 2D XCD-chunked block remap: xcd = bid&7 owns an (mt-chunk x ntk-chunk)
//      rectangle per expert, mt iterates fastest -> B panels and A chunks stay
//      L2-resident per XCD instead of re-fetching from LLC.
//  (2) sched_barrier(0) after the early ldreg pins the prefetch issue point.
template<int KD, int ND, bool FC1, int KSPL>
__global__ __launch_bounds__(256, 3) void k_gemm6(
    const u16* __restrict__ A, const u16* __restrict__ Bt,
    const float* __restrict__ bias, const int* __restrict__ meta,
    const int* __restrict__ gtok, const float* __restrict__ gw,
    u16* __restrict__ Mid, float* __restrict__ out)
{
  constexpr int NT   = ND/128;        // nt tiles
  constexpr int NTK  = NT*KSPL;       // nt x kc slots
  constexpr int MT   = ROWS_CAP/128;  // 72
  constexpr int MTC  = MT/4;          // 18 (4 mt-chunks)
  constexpr int NTKC = NTK/2;         // 2 ntk-chunks

  const int bid = blockIdx.x;
  const int xcd = bid & 7;
  const int s   = bid >> 3;
  const int ntk_l = s / (Ed*MTC);
  const int rem   = s - ntk_l*(Ed*MTC);
  const int e     = rem / MTC;
  const int mt    = (xcd >> 1)*MTC + (rem - e*MTC);
  const int ntk   = (xcd & 1)*NTKC + ntk_l;
  const int nt    = ntk % NT;
  const int kc    = ntk / NT;

  const int p0 = meta[e];
  const int pcnt = meta[e+1] - p0;
  if (mt*128 >= pcnt) return;
  const int row0 = p0 + mt*128;

  __shared__ __attribute__((aligned(16))) u16 As[128*64];  // 16 KB
  __shared__ __attribute__((aligned(16))) u16 Bs[128*64];  // 16 KB

  const int tid = threadIdx.x;
  const int lane = tid & 63, wid = tid >> 6;
  const int wm = wid >> 1, wn = wid & 1;
  const int l15 = lane & 15, l4 = lane >> 4;

  f32x4 acc[4][4] = {};

  const u16* Ap  = A  + (size_t)row0*KD;
  const u16* Btp = Bt + ((size_t)e*ND + (size_t)nt*128)*KD;

  const int ktn = KD/64/KSPL;
  const int kt0 = kc * ktn;
  const int kt1 = kt0 + ktn;

  const int trow = tid >> 3;
  const int tch  = tid & 7;

  u32x4 ra[4], rb[4];

  // prologue: stage tile kt0
#pragma unroll
  for (int j=0;j<4;j++){
    const size_t off = (size_t)(j*32 + trow)*KD + (size_t)kt0*64 + tch*8;
    ra[j] = *(const u32x4*)(Ap + off);
    rb[j] = *(const u32x4*)(Btp + off);
  }
#pragma unroll
  for (int j=0;j<4;j++){
    *(u32x4*)(&As[(j*256+tid)*8]) = ra[j];
    *(u32x4*)(&Bs[(j*256+tid)*8]) = rb[j];
  }
  __syncthreads();

#pragma unroll 1
  for (int kt=kt0; kt<kt1; ++kt){
    // issue next tile's loads early (hide under compute); pin the issue point
    if (kt+1 < kt1){
#pragma unroll
      for (int j=0;j<4;j++){
        const size_t off = (size_t)(j*32 + trow)*KD + (size_t)(kt+1)*64 + tch*8;
        ra[j] = *(const u32x4*)(Ap + off);
        rb[j] = *(const u32x4*)(Btp + off);
      }
      __builtin_amdgcn_sched_barrier(0);
    }
    // compute current tile from LDS
#pragma unroll
    for (int ks=0; ks<2; ++ks){
      bf16x8 af[4], bfv[4];
#pragma unroll
      for (int mi=0;mi<4;mi++){
        const int r  = wm*64 + mi*16 + l15;
        const int cb = (ks*4 + l4) ^ (r & 7);
        af[mi] = __builtin_bit_cast(bf16x8, *(const u16x8*)(&As[r*64 + cb*8]));
      }
#pragma unroll
      for (int ni=0;ni<4;ni++){
        const int n  = wn*64 + ni*16 + l15;
        const int cb = (ks*4 + l4) ^ (n & 7);
        bfv[ni] = __builtin_bit_cast(bf16x8, *(const u16x8*)(&Bs[n*64 + cb*8]));
      }
#pragma unroll
      for (int mi=0;mi<4;mi++)
#pragma unroll
        for (int ni=0;ni<4;ni++)
          acc[mi][ni] = __builtin_amdgcn_mfma_f32_16x16x32_bf16(af[mi], bfv[ni], acc[mi][ni], 0, 0, 0);
    }
    __syncthreads();                 // all LDS reads done
    if (kt+1 < kt1){
#pragma unroll
      for (int j=0;j<4;j++){
        *(u32x4*)(&As[(j*256+tid)*8]) = ra[j];
        *(u32x4*)(&Bs[(j*256+tid)*8]) = rb[j];
      }
      __syncthreads();               // staged tile visible
    }
  }

  if (FC1){
#pragma unroll
    for (int mi=0;mi<4;mi++){
      const int grow = row0 + wm*64 + mi*16 + l4*4;
#pragma unroll
      for (int ni=0;ni<4;ni++){
        const int col = nt*128 + wn*64 + ni*16 + l15;
        const float bv = bias[e*ND + col];
#pragma unroll
        for (int j=0;j<4;j++){
          const float v = acc[mi][ni][j] + bv;
          // gelu(tanh) = v * sigmoid(2*0.79788456*(v + 0.044715 v^3))
          const float z = 0.7978845608028654f * (v + 0.044715f*v*v*v);
          const float g = v / (1.f + __expf(-2.f*z));
          const int gr = grow + j;
          const int cc = col >> 3;
          const int ccs = (cc & ~7) | ((cc ^ gr) & 7);
          Mid[(size_t)gr*Fd + ccs*8 + (col&7)] = f2bf(g);
        }
      }
    }
  } else {
#pragma unroll
    for (int mi=0;mi<4;mi++){
#pragma unroll
      for (int j=0;j<4;j++){
        const int gr = row0 + wm*64 + mi*16 + l4*4 + j;
        const int t = gtok[gr];
        if (t < 0) continue;
        const float wt = gw[gr];
#pragma unroll
        for (int ni=0;ni<4;ni++){
          const int col = nt*128 + wn*64 + ni*16 + l15;
          const float bv = (kc == 0) ? bias[e*ND + col] : 0.f;
          const float v = acc[mi][ni][j] + bv;
          atomicAdd(out + (size_t)t*Hd + col, v*wt);
        }
      }
    }
  }
}

// ---------------- fallback GEMM (ws too small): 128x128, in-kernel B convert --
template<int KD, int ND, bool FC1, int KSPL>
__global__ __launch_bounds__(256) void k_gemm_fb(
    const u16* __restrict__ A, const float* __restrict__ B,
    const float* __restrict__ bias, const int* __restrict__ meta,
    const int* __restrict__ gtok, const float* __restrict__ gw,
    u16* __restrict__ Mid, float* __restrict__ out)
{
  const int e = blockIdx.z, mt = blockIdx.y;
  const int nt = blockIdx.x % (ND/128);
  const int kc = blockIdx.x / (ND/128);
  const int p0 = meta[e];
  const int pcnt = meta[e+1] - p0;
  if (mt*128 >= pcnt) return;
  const int row0 = p0 + mt*128;

  __shared__ __attribute__((aligned(16))) u16 As1[128*64];
  __shared__ __attribute__((aligned(16))) u16 Bs1[128*64];

  const int tid = threadIdx.x;
  const int lane = tid & 63, wid = tid >> 6;
  const int wm = wid >> 1, wn = wid & 1;
  const int l15 = lane & 15, l4 = lane >> 4;

  f32x4 acc[4][4] = {};

  const int sbn = (tid & 63) << 1;
  const int skg = tid >> 6;
  const float* Bp = B + (size_t)e*KD*ND + (size_t)nt*128;
  const int kt0 = kc * (KD/64/KSPL);
  const int kt1 = kt0 + (KD/64/KSPL);

  for (int kt=kt0; kt<kt1; ++kt){
    __syncthreads();
#pragma unroll
    for (int j=0;j<4;j++){
      const int cidx = j*256 + tid;
      gll16(A + (size_t)(row0 + (cidx>>3))*KD + kt*64 + (cidx&7)*8, &As1[cidx*8]);
    }
    {
      const float* bsrc = Bp + (size_t)(kt*64 + skg*16)*ND + sbn;
      u32 ra[8], rb[8];
#pragma unroll
      for (int i=0;i<16;i++){
        const f32x2 v = *(const f32x2*)(bsrc + (size_t)i*ND);
        const u32 lo = f2bf(v[0]), hi = f2bf(v[1]);
        if (i & 1){ ra[i>>1] |= lo<<16; rb[i>>1] |= hi<<16; }
        else      { ra[i>>1]  = lo;     rb[i>>1]  = hi;     }
      }
#pragma unroll
      for (int cl=0; cl<2; ++cl){
        const int cb = skg*2 + cl;
        const u32x4 va = { ra[cl*4], ra[cl*4+1], ra[cl*4+2], ra[cl*4+3] };
        const u32x4 vb = { rb[cl*4], rb[cl*4+1], rb[cl*4+2], rb[cl*4+3] };
        *(u32x4*)(&Bs1[(size_t)sbn    *64 + (cb ^ ( sbn   &7))*8]) = va;
        *(u32x4*)(&Bs1[(size_t)(sbn+1)*64 + (cb ^ ((sbn+1)&7))*8]) = vb;
      }
    }
    __syncthreads();
#pragma unroll
    for (int ks=0; ks<2; ++ks){
      bf16x8 af[4], bfv[4];
#pragma unroll
      for (int mi=0;mi<4;mi++){
        const int r  = wm*64 + mi*16 + l15;
        const int cb = (ks*4 + l4) ^ (r & 7);
        af[mi] = __builtin_bit_cast(bf16x8, *(const u16x8*)(&As1[r*64 + cb*8]));
      }
#pragma unroll
      for (int ni=0;ni<4;ni++){
        const int n  = wn*64 + ni*16 + l15;
        const int cb = (ks*4 + l4) ^ (n & 7);
        bfv[ni] = __builtin_bit_cast(bf16x8, *(const u16x8*)(&Bs1[n*64 + cb*8]));
      }
#pragma unroll
      for (int mi=0;mi<4;mi++)
#pragma unroll
        for (int ni=0;ni<4;ni++)
          acc[mi][ni] = __builtin_amdgcn_mfma_f32_16x16x32_bf16(af[mi], bfv[ni], acc[mi][ni], 0, 0, 0);
    }
  }

  if (FC1){
#pragma unroll
    for (int mi=0;mi<4;mi++){
      const int grow = row0 + wm*64 + mi*16 + l4*4;
#pragma unroll
      for (int ni=0;ni<4;ni++){
        const int col = nt*128 + wn*64 + ni*16 + l15;
        const float bv = bias[e*ND + col];
#pragma unroll
        for (int j=0;j<4;j++){
          const float v = acc[mi][ni][j] + bv;
          const float z = 0.7978845608028654f * (v + 0.044715f*v*v*v);
          const float g = v / (1.f + __expf(-2.f*z));
          const int gr = grow + j;
          const int cc = col >> 3;
          const int ccs = (cc & ~7) | ((cc ^ gr) & 7);
          Mid[(size_t)gr*Fd + ccs*8 + (col&7)] = f2bf(g);
        }
      }
    }
  } else {
#pragma unroll
    for (int mi=0;mi<4;mi++){
#pragma unroll
      for (int j=0;j<4;j++){
        const int gr = row0 + wm*64 + mi*16 + l4*4 + j;
        const int t = gtok[gr];
        if (t < 0) continue;
        const float wt = gw[gr];
#pragma unroll
        for (int ni=0;ni<4;ni++){
          const int col = nt*128 + wn*64 + ni*16 + l15;
          const float bv = (kc == 0) ? bias[e*ND + col] : 0.f;
          const float v = acc[mi][ni][j] + bv;
          atomicAdd(out + (size_t)t*Hd + col, v*wt);
        }
      }
    }
  }
}

// ---------------- launcher ---------------------------------------------------
extern "C" void kernel_launch(void* const* d_in, const int* in_sizes, int n_in,
                              void* d_out, int out_size, void* d_ws, size_t ws_size,
                              hipStream_t stream)
{
  const float* x     = (const float*)d_in[0];
  const float* Wg    = (const float*)d_in[1];
  const float* alpha = (const float*)d_in[2];
  const float* lnw   = (const float*)d_in[3];
  const float* lnb   = (const float*)d_in[4];
  const float* w1    = (const float*)d_in[5];
  const float* b1    = (const float*)d_in[6];
  const float* w2    = (const float*)d_in[7];
  const float* b2    = (const float*)d_in[8];
  float* out = (float*)d_out;
  char* ws = (char*)d_ws;

  float* mu    = (float*)(ws + 0);
  float* rstd  = (float*)(ws + (16<<10));
  int*   tok_e = (int*)  (ws + (32<<10));
  float* tok_w = (float*)(ws + (64<<10));
  int*   meta  = (int*)  (ws + (96<<10));
  int*   cnt   = (int*)  (ws + (97<<10));     // 16 chunks x 8 experts
  int*   base  = (int*)  (ws + (98<<10));     // 16 x 8 scatter offsets
  int*   gtok  = (int*)  (ws + (100<<10));
  float* gw    = (float*)(ws + (144<<10));
  u16*   Xg    = (u16*)  (ws + (192<<10));
  const size_t xg_b   = 2*(size_t)ROWS_CAP*Hd;   // 18.9 MB
  const size_t mid_b  = 2*(size_t)ROWS_CAP*Fd;   // 75.5 MB
  const size_t wt_b   = 2*(size_t)Ed*Hd*Fd;      // 67.1 MB each
  u16*   Amid  = (u16*)  (ws + (192<<10) + xg_b);
  u16*   Wt2   = (u16*)  (ws + (192<<10) + xg_b + mid_b);
  u16*   Wt1   = (u16*)  (ws + (192<<10) + xg_b + mid_b + wt_b);

  const size_t base_need = (192<<10) + xg_b + mid_b;
  if (ws_size < base_need){
    fprintf(stderr, "kernel_launch: ws_size %zu < needed %zu\n", ws_size, base_need);
    return;
  }
  const bool cv2 = ws_size >= base_need + wt_b;        // convert w2
  const bool cv1 = ws_size >= base_need + 2*wt_b;      // convert w1 too

  hipMemsetAsync(d_out, 0, (size_t)out_size*sizeof(float), stream);
  hipMemsetAsync(gtok, 0xFF, (size_t)ROWS_CAP*sizeof(int), stream);   // -1 pads
  hipMemsetAsync(gw,   0x00, (size_t)ROWS_CAP*sizeof(float), stream);

  if (cv2) k_wt<Fd, Hd><<<dim3(Fd/64, Hd/64, Ed), 256, 0, stream>>>(w2, Wt2);
  if (cv1) k_wt<Hd, Fd><<<dim3(Hd/64, Fd/64, Ed), 256, 0, stream>>>(w1, Wt1);
  k_gate   <<<Td, 256, 0, stream>>>(x, Wg, alpha, mu, rstd, tok_e, tok_w);
  k_hist   <<<Td/256, 256, 0, stream>>>(tok_e, cnt);
  k_scan   <<<1, 64, 0, stream>>>(cnt, meta, base);
  k_scatter<<<Td/256, 256, 0, stream>>>(tok_e, tok_w, base, gtok, gw);
  k_gather <<<ROWS_CAP, 256, 0, stream>>>(x, lnw, lnb, mu, rstd, meta, gtok, Xg);

  // 1D grids for the XCD-chunked remap: 8 xcd * (NTK/2) * Ed * (MT/4)
  const int g1 = 8 * ((Fd/128)*1/2) * Ed * ((ROWS_CAP/128)/4);   // fc1: 18432
  const int g2 = 8 * ((Hd/128)*2/2) * Ed * ((ROWS_CAP/128)/4);   // fc2: 9216

  if (cv1)
    k_gemm6<Hd, Fd, true, 1><<<g1, 256, 0, stream>>>(
        Xg, Wt1, b1, meta, gtok, gw, Amid, nullptr);
  else
    k_gemm_fb<Hd, Fd, true, 1><<<dim3(Fd/128, ROWS_CAP/128, Ed), 256, 0, stream>>>(
        Xg, w1, b1, meta, gtok, gw, Amid, nullptr);

  if (cv2)
    k_gemm6<Fd, Hd, false, 2><<<g2, 256, 0, stream>>>(
        Amid, Wt2, b2, meta, gtok, gw, nullptr, out);
  else
    k_gemm_fb<Fd, Hd, false, 2><<<dim3((Hd/128)*2, ROWS_CAP/128, Ed), 256, 0, stream>>>(
        Amid, w2, b2, meta, gtok, gw, nullptr, out);
}

// Round 10
// 610.095 us; speedup vs baseline: 1.5207x; 1.5207x over previous
//
#include <hip/hip_runtime.h>
#include <stdint.h>
#include <stdio.h>

#define Td 4096
#define Hd 1024
#define Ed 8
#define Fd 4096
#define ROWS_CAP 9216   // 8192 pairs + 8*128 alignment slack

typedef unsigned int u32;
typedef unsigned short u16;
typedef float f32x4 __attribute__((ext_vector_type(4)));
typedef float f32x2 __attribute__((ext_vector_type(2)));
typedef __bf16 bf16x8 __attribute__((ext_vector_type(8)));
typedef u16 u16x8 __attribute__((ext_vector_type(8)));
typedef u16 u16x4 __attribute__((ext_vector_type(4)));
typedef u32 u32x4 __attribute__((ext_vector_type(4)));

#define ASG __attribute__((address_space(1)))
#define ASL __attribute__((address_space(3)))

__device__ __forceinline__ void gll16(const void* g, void* l) {
  __builtin_amdgcn_global_load_lds((const ASG u32*)g, (ASL u32*)l, 16, 0, 0);
}

__device__ __forceinline__ u16 f2bf(float f) {
  u32 u = __float_as_uint(f);
  u = u + 0x7fffu + ((u >> 16) & 1u);
  return (u16)(u >> 16);
}

// ---------------- gate: logits (f64 accum), top-2, softmax*alpha, LN stats ----
__global__ __launch_bounds__(256) void k_gate(const float* __restrict__ x,
    const float* __restrict__ Wg, const float* __restrict__ alpha,
    float* __restrict__ mu, float* __restrict__ rstd,
    int* __restrict__ tok_e, float* __restrict__ tok_w)
{
  const int t = blockIdx.x, tid = threadIdx.x;
  const f32x4 xv = *(const f32x4*)(x + (size_t)t*Hd + tid*4);
  float s1 = 0.f, s2 = 0.f;
  double lg[8];
#pragma unroll
  for (int e=0;e<8;e++) lg[e]=0.0;
#pragma unroll
  for (int i=0;i<4;i++){
    const float xi = xv[i];
    s1 += xi; s2 += xi*xi;
    const f32x4 wa = *(const f32x4*)(Wg + (size_t)(tid*4+i)*Ed);
    const f32x4 wb = *(const f32x4*)(Wg + (size_t)(tid*4+i)*Ed + 4);
    lg[0] += (double)xi*(double)wa[0]; lg[1] += (double)xi*(double)wa[1];
    lg[2] += (double)xi*(double)wa[2]; lg[3] += (double)xi*(double)wa[3];
    lg[4] += (double)xi*(double)wb[0]; lg[5] += (double)xi*(double)wb[1];
    lg[6] += (double)xi*(double)wb[2]; lg[7] += (double)xi*(double)wb[3];
  }
#pragma unroll
  for (int off=32; off>0; off>>=1){
    s1 += __shfl_down(s1, off);
    s2 += __shfl_down(s2, off);
#pragma unroll
    for (int e=0;e<8;e++) lg[e] += __shfl_down(lg[e], off);
  }
  __shared__ double sl[4][8];
  __shared__ float sa[4], sb[4];
  const int w = tid>>6, lane = tid&63;
  if (lane==0){
#pragma unroll
    for (int e=0;e<8;e++) sl[w][e]=lg[e];
    sa[w]=s1; sb[w]=s2;
  }
  __syncthreads();
  if (tid==0){
    float S1=0.f,S2=0.f; double L[8];
#pragma unroll
    for (int e=0;e<8;e++) L[e]=0.0;
#pragma unroll
    for (int i=0;i<4;i++){
      S1+=sa[i]; S2+=sb[i];
#pragma unroll
      for (int e=0;e<8;e++) L[e]+=sl[i][e];
    }
    const float mean = S1 * (1.f/Hd);
    float var = S2 * (1.f/Hd) - mean*mean;
    if (var < 0.f) var = 0.f;
    mu[t]=mean; rstd[t]=rsqrtf(var + 1e-5f);
    float l[8];
#pragma unroll
    for (int e=0;e<8;e++) l[e]=(float)L[e];
    int e0=0;
#pragma unroll
    for (int e=1;e<8;e++) if (l[e]>l[e0]) e0=e;
    int e1=-1;
#pragma unroll
    for (int e=0;e<8;e++) if (e!=e0 && (e1<0 || l[e]>l[e1])) e1=e;
    const float p = __expf(l[e1]-l[e0]);     // <= 1
    const float inv = 1.f/(1.f+p);
    tok_e[2*t]=e0; tok_e[2*t+1]=e1;
    tok_w[2*t]   = inv   * alpha[e0];
    tok_w[2*t+1] = p*inv * alpha[e1];
  }
}

// ---------------- parallel deterministic routing -----------------------------
__global__ __launch_bounds__(256) void k_hist(const int* __restrict__ tok_e,
                                              int* __restrict__ cnt)
{
  __shared__ int c[8];
  const int tid = threadIdx.x, ch = blockIdx.x;
  if (tid < 8) c[tid] = 0;
  __syncthreads();
  const int t = ch*256 + tid;
  atomicAdd(&c[tok_e[2*t]], 1);
  atomicAdd(&c[tok_e[2*t+1]], 1);
  __syncthreads();
  if (tid < 8) cnt[ch*8 + tid] = c[tid];
}

__global__ __launch_bounds__(64) void k_scan(const int* __restrict__ cnt,
                                             int* __restrict__ meta,
                                             int* __restrict__ base)
{
  if (threadIdx.x != 0) return;
  int s = 0;
  for (int e=0;e<8;e++){
    meta[e] = s;
    int run = s;
    for (int ch=0; ch<Td/256; ++ch){
      base[ch*8+e] = run;
      run += cnt[ch*8+e];
    }
    s += (run - s + 127) & ~127;     // 128-row alignment for 128-tile GEMM
  }
  meta[8] = s;
}

__global__ __launch_bounds__(256) void k_scatter(const int* __restrict__ tok_e,
    const float* __restrict__ tok_w, const int* __restrict__ base,
    int* __restrict__ gtok, float* __restrict__ gw)
{
  __shared__ int wsum[4];
  const int tid = threadIdx.x, ch = blockIdx.x, w = tid>>6, lane = tid&63;
  const int t = ch*256 + tid;
  const int e0 = tok_e[2*t], e1 = tok_e[2*t+1];
  for (int e=0;e<8;e++){
    const bool fa = (e0 == e);
    const bool f  = fa || (e1 == e);
    const unsigned long long bal = __ballot(f);
    if (lane==0) wsum[w] = __popcll(bal);
    __syncthreads();
    int pre=0;
#pragma unroll
    for (int i=0;i<4;i++){ if (i<w) pre += wsum[i]; }
    if (f){
      const int pos = base[ch*8+e] + pre + __popcll(bal & ((1ull<<lane)-1ull));
      gtok[pos] = t;
      gw[pos]   = tok_w[2*t + (fa?0:1)];
    }
    __syncthreads();
  }
}

// ---------------- gather + LayerNorm -> bf16 Xg (chunk-swizzled) -------------
__global__ __launch_bounds__(256) void k_gather(const float* __restrict__ x,
    const float* __restrict__ lnw, const float* __restrict__ lnb,
    const float* __restrict__ mu, const float* __restrict__ rstd,
    const int* __restrict__ meta, const int* __restrict__ gtok,
    u16* __restrict__ Xg)
{
  const int r = blockIdx.x, tid = threadIdx.x;
  __shared__ int ps[9];
  if (tid < 9) ps[tid] = meta[tid];
  __syncthreads();
  if (r >= ps[8]) return;
  int e = 0;
#pragma unroll
  for (int i=1;i<8;i++) if (r >= ps[i]) e = i;
  const int k0 = tid*4;
  const int c  = k0 >> 3;
  const int cs = (c & ~7) | ((c ^ r) & 7);       // XOR-swizzle 16B chunks in 128B blocks
  u16* dst = Xg + (size_t)r*Hd + cs*8 + (k0 & 7);
  const int t = gtok[r];
  u16x4 o;
  if (t < 0){
    o[0]=0;o[1]=0;o[2]=0;o[3]=0;
  } else {
    const float m = mu[t], s = rstd[t];
    const f32x4 xv = *(const f32x4*)(x   + (size_t)t*Hd + k0);
    const f32x4 wv = *(const f32x4*)(lnw + (size_t)e*Hd + k0);
    const f32x4 bv = *(const f32x4*)(lnb + (size_t)e*Hd + k0);
#pragma unroll
    for (int i=0;i<4;i++) o[i] = f2bf((xv[i]-m)*s*wv[i] + bv[i]);
  }
  *(u16x4*)dst = o;
}

// ---------------- weight prepass: [e][K][N] f32 -> [e][N][K] bf16, swizzled --
template<int K, int N>
__global__ __launch_bounds__(256) void k_wt(const float* __restrict__ W,
                                            u16* __restrict__ Wt)
{
  const int e = blockIdx.z, kb = blockIdx.x*64, nb = blockIdx.y*64;
  __shared__ u16 T[64*66];
  const int tid = threadIdx.x;
#pragma unroll
  for (int j=0;j<8;j++){
    const int idx = j*256 + tid;          // 2048 f32x2 pairs
    const int k = idx >> 5;               // 0..63
    const int n = (idx & 31) << 1;        // 0..62 even
    const f32x2 v = *(const f32x2*)(W + ((size_t)e*K + kb + k)*N + nb + n);
    T[n*66 + k]     = f2bf(v[0]);
    T[(n+1)*66 + k] = f2bf(v[1]);
  }
  __syncthreads();
  const int nl = tid >> 2;
  const int gn = nb + nl;
  u16* dstrow = Wt + ((size_t)e*N + gn)*K;
#pragma unroll
  for (int cc=0; cc<2; ++cc){
    const int c = ((tid & 3) << 1) + cc;  // local chunk 0..7
    u32x4 v;
#pragma unroll
    for (int i=0;i<4;i++) v[i] = *(const u32*)&T[nl*66 + c*8 + i*2];
    const int cabs = (kb >> 3) + c;
    const int cs = (cabs & ~7) | ((cabs ^ gn) & 7);
    *(u32x4*)(dstrow + cs*8) = v;
  }
}

// ---------------- grouped GEMM: 128x128, BK=64, 4 waves, REG-STAGED depth-2 --
// R6 structure (best measured) + (a) flat global-tile grid: blockIdx.y = gt
// indexes REAL 128-row tiles (segments 128-aligned, ~72 total) -> zero empty
// blocks, dense dispatch; (b) prefetch depth 2 with two named register sets:
// ds_write consumes loads issued ~2 compute phases earlier (~700-900 cy cover
// vs R6's ~350) to hide HBM latency on the streaming A/B panels.
template<int KD, int ND, bool FC1, int KSPL>
__global__ __launch_bounds__(256, 3) void k_gemm7(
    const u16* __restrict__ A, const u16* __restrict__ Bt,
    const float* __restrict__ bias, const int* __restrict__ meta,
    const int* __restrict__ gtok, const float* __restrict__ gw,
    u16* __restrict__ Mid, float* __restrict__ out)
{
  constexpr int NT = ND/128;
  const int nt = blockIdx.x % NT;
  const int kc = blockIdx.x / NT;
  const int gt = blockIdx.y;

  __shared__ int ps[9];
  const int tid = threadIdx.x;
  if (tid < 9) ps[tid] = meta[tid];
  __syncthreads();
  const int row0 = gt*128;
  if (row0 >= ps[8]) return;
  int e = 0;
#pragma unroll
  for (int i=1;i<8;i++) if (row0 >= ps[i]) e = i;

  __shared__ __attribute__((aligned(16))) u16 As[128*64];  // 16 KB
  __shared__ __attribute__((aligned(16))) u16 Bs[128*64];  // 16 KB

  const int lane = tid & 63, wid = tid >> 6;
  const int wm = wid >> 1, wn = wid & 1;
  const int l15 = lane & 15, l4 = lane >> 4;

  f32x4 acc[4][4] = {};

  const u16* Ap  = A  + (size_t)row0*KD;
  const u16* Btp = Bt + ((size_t)e*ND + (size_t)nt*128)*KD;

  const int ktn = KD/64/KSPL;
  const int kt0 = kc * ktn;
  const int kt1 = kt0 + ktn;
  static_assert((KD/64/KSPL) >= 4 && (KD/64/KSPL) % 2 == 0, "kt count");

  const int trow = tid >> 3;
  const int tch  = tid & 7;

  u32x4 raA[4], rbA[4], raB[4], rbB[4];   // two named prefetch sets (rule #20)

  auto ldA = [&](int kt){
#pragma unroll
    for (int j=0;j<4;j++){
      const size_t off = (size_t)(j*32 + trow)*KD + (size_t)kt*64 + tch*8;
      raA[j] = *(const u32x4*)(Ap + off);
      rbA[j] = *(const u32x4*)(Btp + off);
    }
    __builtin_amdgcn_sched_barrier(0);
  };
  auto ldB = [&](int kt){
#pragma unroll
    for (int j=0;j<4;j++){
      const size_t off = (size_t)(j*32 + trow)*KD + (size_t)kt*64 + tch*8;
      raB[j] = *(const u32x4*)(Ap + off);
      rbB[j] = *(const u32x4*)(Btp + off);
    }
    __builtin_amdgcn_sched_barrier(0);
  };
  auto dswrA = [&](){
#pragma unroll
    for (int j=0;j<4;j++){
      *(u32x4*)(&As[(j*256+tid)*8]) = raA[j];
      *(u32x4*)(&Bs[(j*256+tid)*8]) = rbA[j];
    }
  };
  auto dswrB = [&](){
#pragma unroll
    for (int j=0;j<4;j++){
      *(u32x4*)(&As[(j*256+tid)*8]) = raB[j];
      *(u32x4*)(&Bs[(j*256+tid)*8]) = rbB[j];
    }
  };
  auto compute = [&](){
#pragma unroll
    for (int ks=0; ks<2; ++ks){
      bf16x8 af[4], bfv[4];
#pragma unroll
      for (int mi=0;mi<4;mi++){
        const int r  = wm*64 + mi*16 + l15;
        const int cb = (ks*4 + l4) ^ (r & 7);
        af[mi] = __builtin_bit_cast(bf16x8, *(const u16x8*)(&As[r*64 + cb*8]));
      }
#pragma unroll
      for (int ni=0;ni<4;ni++){
        const int n  = wn*64 + ni*16 + l15;
        const int cb = (ks*4 + l4) ^ (n & 7);
        bfv[ni] = __builtin_bit_cast(bf16x8, *(const u16x8*)(&Bs[n*64 + cb*8]));
      }
#pragma unroll
      for (int mi=0;mi<4;mi++)
#pragma unroll
        for (int ni=0;ni<4;ni++)
          acc[mi][ni] = __builtin_amdgcn_mfma_f32_16x16x32_bf16(af[mi], bfv[ni], acc[mi][ni], 0, 0, 0);
    }
  };

  // prologue: set A <- kt0 (write now), set B <- kt0+1 (in flight)
  ldA(kt0);
  ldB(kt0+1);
  dswrA();                 // compiler waits vmcnt on set-A regs only
  __syncthreads();

#pragma unroll 1
  for (int kt=kt0; kt<kt1; kt+=2){
    compute();                         // LDS = kt
    if (kt+2 < kt1) ldA(kt+2);         // set A free (kt data already in LDS)
    __syncthreads();                   // all reads of kt done
    dswrB();                           // kt+1 -> LDS (loads ~2 phases old)
    __syncthreads();                   // visible
    compute();                         // LDS = kt+1
    if (kt+3 < kt1) ldB(kt+3);
    __syncthreads();                   // all reads of kt+1 done
    if (kt+2 < kt1){
      dswrA();                         // kt+2 -> LDS
      __syncthreads();                 // visible for next iter
    }
  }

  if (FC1){
#pragma unroll
    for (int mi=0;mi<4;mi++){
      const int grow = row0 + wm*64 + mi*16 + l4*4;
#pragma unroll
      for (int ni=0;ni<4;ni++){
        const int col = nt*128 + wn*64 + ni*16 + l15;
        const float bv = bias[e*ND + col];
#pragma unroll
        for (int j=0;j<4;j++){
          const float v = acc[mi][ni][j] + bv;
          // gelu(tanh) = v * sigmoid(2*0.79788456*(v + 0.044715 v^3))
          const float z = 0.7978845608028654f * (v + 0.044715f*v*v*v);
          const float g = v / (1.f + __expf(-2.f*z));
          const int gr = grow + j;
          const int cc = col >> 3;
          const int ccs = (cc & ~7) | ((cc ^ gr) & 7);
          Mid[(size_t)gr*Fd + ccs*8 + (col&7)] = f2bf(g);
        }
      }
    }
  } else {
#pragma unroll
    for (int mi=0;mi<4;mi++){
#pragma unroll
      for (int j=0;j<4;j++){
        const int gr = row0 + wm*64 + mi*16 + l4*4 + j;
        const int t = gtok[gr];
        if (t < 0) continue;
        const float wt = gw[gr];
#pragma unroll
        for (int ni=0;ni<4;ni++){
          const int col = nt*128 + wn*64 + ni*16 + l15;
          const float bv = (kc == 0) ? bias[e*ND + col] : 0.f;
          const float v = acc[mi][ni][j] + bv;
          atomicAdd(out + (size_t)t*Hd + col, v*wt);
        }
      }
    }
  }
}

// ---------------- fallback GEMM (ws too small): 128x128, in-kernel B convert --
template<int KD, int ND, bool FC1, int KSPL>
__global__ __launch_bounds__(256) void k_gemm_fb(
    const u16* __restrict__ A, const float* __restrict__ B,
    const float* __restrict__ bias, const int* __restrict__ meta,
    const int* __restrict__ gtok, const float* __restrict__ gw,
    u16* __restrict__ Mid, float* __restrict__ out)
{
  const int e = blockIdx.z, mt = blockIdx.y;
  const int nt = blockIdx.x % (ND/128);
  const int kc = blockIdx.x / (ND/128);
  const int p0 = meta[e];
  const int pcnt = meta[e+1] - p0;
  if (mt*128 >= pcnt) return;
  const int row0 = p0 + mt*128;

  __shared__ __attribute__((aligned(16))) u16 As1[128*64];
  __shared__ __attribute__((aligned(16))) u16 Bs1[128*64];

  const int tid = threadIdx.x;
  const int lane = tid & 63, wid = tid >> 6;
  const int wm = wid >> 1, wn = wid & 1;
  const int l15 = lane & 15, l4 = lane >> 4;

  f32x4 acc[4][4] = {};

  const int sbn = (tid & 63) << 1;
  const int skg = tid >> 6;
  const float* Bp = B + (size_t)e*KD*ND + (size_t)nt*128;
  const int kt0 = kc * (KD/64/KSPL);
  const int kt1 = kt0 + (KD/64/KSPL);

  for (int kt=kt0; kt<kt1; ++kt){
    __syncthreads();
#pragma unroll
    for (int j=0;j<4;j++){
      const int cidx = j*256 + tid;
      gll16(A + (size_t)(row0 + (cidx>>3))*KD + kt*64 + (cidx&7)*8, &As1[cidx*8]);
    }
    {
      const float* bsrc = Bp + (size_t)(kt*64 + skg*16)*ND + sbn;
      u32 ra[8], rb[8];
#pragma unroll
      for (int i=0;i<16;i++){
        const f32x2 v = *(const f32x2*)(bsrc + (size_t)i*ND);
        const u32 lo = f2bf(v[0]), hi = f2bf(v[1]);
        if (i & 1){ ra[i>>1] |= lo<<16; rb[i>>1] |= hi<<16; }
        else      { ra[i>>1]  = lo;     rb[i>>1]  = hi;     }
      }
#pragma unroll
      for (int cl=0; cl<2; ++cl){
        const int cb = skg*2 + cl;
        const u32x4 va = { ra[cl*4], ra[cl*4+1], ra[cl*4+2], ra[cl*4+3] };
        const u32x4 vb = { rb[cl*4], rb[cl*4+1], rb[cl*4+2], rb[cl*4+3] };
        *(u32x4*)(&Bs1[(size_t)sbn    *64 + (cb ^ ( sbn   &7))*8]) = va;
        *(u32x4*)(&Bs1[(size_t)(sbn+1)*64 + (cb ^ ((sbn+1)&7))*8]) = vb;
      }
    }
    __syncthreads();
#pragma unroll
    for (int ks=0; ks<2; ++ks){
      bf16x8 af[4], bfv[4];
#pragma unroll
      for (int mi=0;mi<4;mi++){
        const int r  = wm*64 + mi*16 + l15;
        const int cb = (ks*4 + l4) ^ (r & 7);
        af[mi] = __builtin_bit_cast(bf16x8, *(const u16x8*)(&As1[r*64 + cb*8]));
      }
#pragma unroll
      for (int ni=0;ni<4;ni++){
        const int n  = wn*64 + ni*16 + l15;
        const int cb = (ks*4 + l4) ^ (n & 7);
        bfv[ni] = __builtin_bit_cast(bf16x8, *(const u16x8*)(&Bs1[n*64 + cb*8]));
      }
#pragma unroll
      for (int mi=0;mi<4;mi++)
#pragma unroll
        for (int ni=0;ni<4;ni++)
          acc[mi][ni] = __builtin_amdgcn_mfma_f32_16x16x32_bf16(af[mi], bfv[ni], acc[mi][ni], 0, 0, 0);
    }
  }

  if (FC1){
#pragma unroll
    for (int mi=0;mi<4;mi++){
      const int grow = row0 + wm*64 + mi*16 + l4*4;
#pragma unroll
      for (int ni=0;ni<4;ni++){
        const int col = nt*128 + wn*64 + ni*16 + l15;
        const float bv = bias[e*ND + col];
#pragma unroll
        for (int j=0;j<4;j++){
          const float v = acc[mi][ni][j] + bv;
          const float z = 0.7978845608028654f * (v + 0.044715f*v*v*v);
          const float g = v / (1.f + __expf(-2.f*z));
          const int gr = grow + j;
          const int cc = col >> 3;
          const int ccs = (cc & ~7) | ((cc ^ gr) & 7);
          Mid[(size_t)gr*Fd + ccs*8 + (col&7)] = f2bf(g);
        }
      }
    }
  } else {
#pragma unroll
    for (int mi=0;mi<4;mi++){
#pragma unroll
      for (int j=0;j<4;j++){
        const int gr = row0 + wm*64 + mi*16 + l4*4 + j;
        const int t = gtok[gr];
        if (t < 0) continue;
        const float wt = gw[gr];
#pragma unroll
        for (int ni=0;ni<4;ni++){
          const int col = nt*128 + wn*64 + ni*16 + l15;
          const float bv = (kc == 0) ? bias[e*ND + col] : 0.f;
          const float v = acc[mi][ni][j] + bv;
          atomicAdd(out + (size_t)t*Hd + col, v*wt);
        }
      }
    }
  }
}

// ---------------- launcher ---------------------------------------------------
extern "C" void kernel_launch(void* const* d_in, const int* in_sizes, int n_in,
                              void* d_out, int out_size, void* d_ws, size_t ws_size,
                              hipStream_t stream)
{
  const float* x     = (const float*)d_in[0];
  const float* Wg    = (const float*)d_in[1];
  const float* alpha = (const float*)d_in[2];
  const float* lnw   = (const float*)d_in[3];
  const float* lnb   = (const float*)d_in[4];
  const float* w1    = (const float*)d_in[5];
  const float* b1    = (const float*)d_in[6];
  const float* w2    = (const float*)d_in[7];
  const float* b2    = (const float*)d_in[8];
  float* out = (float*)d_out;
  char* ws = (char*)d_ws;

  float* mu    = (float*)(ws + 0);
  float* rstd  = (float*)(ws + (16<<10));
  int*   tok_e = (int*)  (ws + (32<<10));
  float* tok_w = (float*)(ws + (64<<10));
  int*   meta  = (int*)  (ws + (96<<10));
  int*   cnt   = (int*)  (ws + (97<<10));     // 16 chunks x 8 experts
  int*   base  = (int*)  (ws + (98<<10));     // 16 x 8 scatter offsets
  int*   gtok  = (int*)  (ws + (100<<10));
  float* gw    = (float*)(ws + (144<<10));
  u16*   Xg    = (u16*)  (ws + (192<<10));
  const size_t xg_b   = 2*(size_t)ROWS_CAP*Hd;   // 18.9 MB
  const size_t mid_b  = 2*(size_t)ROWS_CAP*Fd;   // 75.5 MB
  const size_t wt_b   = 2*(size_t)Ed*Hd*Fd;      // 67.1 MB each
  u16*   Amid  = (u16*)  (ws + (192<<10) + xg_b);
  u16*   Wt2   = (u16*)  (ws + (192<<10) + xg_b + mid_b);
  u16*   Wt1   = (u16*)  (ws + (192<<10) + xg_b + mid_b + wt_b);

  const size_t base_need = (192<<10) + xg_b + mid_b;
  if (ws_size < base_need){
    fprintf(stderr, "kernel_launch: ws_size %zu < needed %zu\n", ws_size, base_need);
    return;
  }
  const bool cv2 = ws_size >= base_need + wt_b;        // convert w2
  const bool cv1 = ws_size >= base_need + 2*wt_b;      // convert w1 too

  hipMemsetAsync(d_out, 0, (size_t)out_size*sizeof(float), stream);
  hipMemsetAsync(gtok, 0xFF, (size_t)ROWS_CAP*sizeof(int), stream);   // -1 pads
  hipMemsetAsync(gw,   0x00, (size_t)ROWS_CAP*sizeof(float), stream);

  if (cv2) k_wt<Fd, Hd><<<dim3(Fd/64, Hd/64, Ed), 256, 0, stream>>>(w2, Wt2);
  if (cv1) k_wt<Hd, Fd><<<dim3(Hd/64, Fd/64, Ed), 256, 0, stream>>>(w1, Wt1);
  k_gate   <<<Td, 256, 0, stream>>>(x, Wg, alpha, mu, rstd, tok_e, tok_w);
  k_hist   <<<Td/256, 256, 0, stream>>>(tok_e, cnt);
  k_scan   <<<1, 64, 0, stream>>>(cnt, meta, base);
  k_scatter<<<Td/256, 256, 0, stream>>>(tok_e, tok_w, base, gtok, gw);
  k_gather <<<ROWS_CAP, 256, 0, stream>>>(x, lnw, lnb, mu, rstd, meta, gtok, Xg);

  if (cv1)
    k_gemm7<Hd, Fd, true, 1><<<dim3(Fd/128, ROWS_CAP/128), 256, 0, stream>>>(
        Xg, Wt1, b1, meta, gtok, gw, Amid, nullptr);
  else
    k_gemm_fb<Hd, Fd, true, 1><<<dim3(Fd/128, ROWS_CAP/128, Ed), 256, 0, stream>>>(
        Xg, w1, b1, meta, gtok, gw, Amid, nullptr);

  if (cv2)
    k_gemm7<Fd, Hd, false, 2><<<dim3((Hd/128)*2, ROWS_CAP/128), 256, 0, stream>>>(
        Amid, Wt2, b2, meta, gtok, gw, nullptr, out);
  else
    k_gemm_fb<Fd, Hd, false, 2><<<dim3((Hd/128)*2, ROWS_CAP/128, Ed), 256, 0, stream>>>(
        Amid, w2, b2, meta, gtok, gw, nullptr, out);
}

// Round 11
// 397.137 us; speedup vs baseline: 2.3362x; 1.5362x over previous
//
#include <hip/hip_runtime.h>
#include <stdint.h>
#include <stdio.h>

#define Td 4096
#define Hd 1024
#define Ed 8
#define Fd 4096
#define ROWS_CAP 9216   // 8192 pairs + 8*128 alignment slack

typedef unsigned int u32;
typedef unsigned short u16;
typedef float f32x4 __attribute__((ext_vector_type(4)));
typedef float f32x2 __attribute__((ext_vector_type(2)));
typedef __bf16 bf16x8 __attribute__((ext_vector_type(8)));
typedef u16 u16x8 __attribute__((ext_vector_type(8)));
typedef u16 u16x4 __attribute__((ext_vector_type(4)));
typedef u32 u32x4 __attribute__((ext_vector_type(4)));

#define ASG __attribute__((address_space(1)))
#define ASL __attribute__((address_space(3)))

__device__ __forceinline__ void gll16(const void* g, void* l) {
  __builtin_amdgcn_global_load_lds((const ASG u32*)g, (ASL u32*)l, 16, 0, 0);
}

__device__ __forceinline__ u16 f2bf(float f) {
  u32 u = __float_as_uint(f);
  u = u + 0x7fffu + ((u >> 16) & 1u);
  return (u16)(u >> 16);
}

// ---------------- gate: logits (f64 accum), top-2, softmax*alpha, LN stats ----
__global__ __launch_bounds__(256) void k_gate(const float* __restrict__ x,
    const float* __restrict__ Wg, const float* __restrict__ alpha,
    float* __restrict__ mu, float* __restrict__ rstd,
    int* __restrict__ tok_e, float* __restrict__ tok_w)
{
  const int t = blockIdx.x, tid = threadIdx.x;
  const f32x4 xv = *(const f32x4*)(x + (size_t)t*Hd + tid*4);
  float s1 = 0.f, s2 = 0.f;
  double lg[8];
#pragma unroll
  for (int e=0;e<8;e++) lg[e]=0.0;
#pragma unroll
  for (int i=0;i<4;i++){
    const float xi = xv[i];
    s1 += xi; s2 += xi*xi;
    const f32x4 wa = *(const f32x4*)(Wg + (size_t)(tid*4+i)*Ed);
    const f32x4 wb = *(const f32x4*)(Wg + (size_t)(tid*4+i)*Ed + 4);
    lg[0] += (double)xi*(double)wa[0]; lg[1] += (double)xi*(double)wa[1];
    lg[2] += (double)xi*(double)wa[2]; lg[3] += (double)xi*(double)wa[3];
    lg[4] += (double)xi*(double)wb[0]; lg[5] += (double)xi*(double)wb[1];
    lg[6] += (double)xi*(double)wb[2]; lg[7] += (double)xi*(double)wb[3];
  }
#pragma unroll
  for (int off=32; off>0; off>>=1){
    s1 += __shfl_down(s1, off);
    s2 += __shfl_down(s2, off);
#pragma unroll
    for (int e=0;e<8;e++) lg[e] += __shfl_down(lg[e], off);
  }
  __shared__ double sl[4][8];
  __shared__ float sa[4], sb[4];
  const int w = tid>>6, lane = tid&63;
  if (lane==0){
#pragma unroll
    for (int e=0;e<8;e++) sl[w][e]=lg[e];
    sa[w]=s1; sb[w]=s2;
  }
  __syncthreads();
  if (tid==0){
    float S1=0.f,S2=0.f; double L[8];
#pragma unroll
    for (int e=0;e<8;e++) L[e]=0.0;
#pragma unroll
    for (int i=0;i<4;i++){
      S1+=sa[i]; S2+=sb[i];
#pragma unroll
      for (int e=0;e<8;e++) L[e]+=sl[i][e];
    }
    const float mean = S1 * (1.f/Hd);
    float var = S2 * (1.f/Hd) - mean*mean;
    if (var < 0.f) var = 0.f;
    mu[t]=mean; rstd[t]=rsqrtf(var + 1e-5f);
    float l[8];
#pragma unroll
    for (int e=0;e<8;e++) l[e]=(float)L[e];
    int e0=0;
#pragma unroll
    for (int e=1;e<8;e++) if (l[e]>l[e0]) e0=e;
    int e1=-1;
#pragma unroll
    for (int e=0;e<8;e++) if (e!=e0 && (e1<0 || l[e]>l[e1])) e1=e;
    const float p = __expf(l[e1]-l[e0]);     // <= 1
    const float inv = 1.f/(1.f+p);
    tok_e[2*t]=e0; tok_e[2*t+1]=e1;
    tok_w[2*t]   = inv   * alpha[e0];
    tok_w[2*t+1] = p*inv * alpha[e1];
  }
}

// ---------------- parallel deterministic routing -----------------------------
__global__ __launch_bounds__(256) void k_hist(const int* __restrict__ tok_e,
                                              int* __restrict__ cnt)
{
  __shared__ int c[8];
  const int tid = threadIdx.x, ch = blockIdx.x;
  if (tid < 8) c[tid] = 0;
  __syncthreads();
  const int t = ch*256 + tid;
  atomicAdd(&c[tok_e[2*t]], 1);
  atomicAdd(&c[tok_e[2*t+1]], 1);
  __syncthreads();
  if (tid < 8) cnt[ch*8 + tid] = c[tid];
}

__global__ __launch_bounds__(64) void k_scan(const int* __restrict__ cnt,
                                             int* __restrict__ meta,
                                             int* __restrict__ base)
{
  if (threadIdx.x != 0) return;
  int s = 0;
  for (int e=0;e<8;e++){
    meta[e] = s;
    int run = s;
    for (int ch=0; ch<Td/256; ++ch){
      base[ch*8+e] = run;
      run += cnt[ch*8+e];
    }
    s += (run - s + 127) & ~127;     // 128-row alignment for 128-tile GEMM
  }
  meta[8] = s;
}

__global__ __launch_bounds__(256) void k_scatter(const int* __restrict__ tok_e,
    const float* __restrict__ tok_w, const int* __restrict__ base,
    int* __restrict__ gtok, float* __restrict__ gw)
{
  __shared__ int wsum[4];
  const int tid = threadIdx.x, ch = blockIdx.x, w = tid>>6, lane = tid&63;
  const int t = ch*256 + tid;
  const int e0 = tok_e[2*t], e1 = tok_e[2*t+1];
  for (int e=0;e<8;e++){
    const bool fa = (e0 == e);
    const bool f  = fa || (e1 == e);
    const unsigned long long bal = __ballot(f);
    if (lane==0) wsum[w] = __popcll(bal);
    __syncthreads();
    int pre=0;
#pragma unroll
    for (int i=0;i<4;i++){ if (i<w) pre += wsum[i]; }
    if (f){
      const int pos = base[ch*8+e] + pre + __popcll(bal & ((1ull<<lane)-1ull));
      gtok[pos] = t;
      gw[pos]   = tok_w[2*t + (fa?0:1)];
    }
    __syncthreads();
  }
}

// ---------------- gather + LayerNorm -> bf16 Xg (chunk-swizzled) -------------
__global__ __launch_bounds__(256) void k_gather(const float* __restrict__ x,
    const float* __restrict__ lnw, const float* __restrict__ lnb,
    const float* __restrict__ mu, const float* __restrict__ rstd,
    const int* __restrict__ meta, const int* __restrict__ gtok,
    u16* __restrict__ Xg)
{
  const int r = blockIdx.x, tid = threadIdx.x;
  __shared__ int ps[9];
  if (tid < 9) ps[tid] = meta[tid];
  __syncthreads();
  if (r >= ps[8]) return;
  int e = 0;
#pragma unroll
  for (int i=1;i<8;i++) if (r >= ps[i]) e = i;
  const int k0 = tid*4;
  const int c  = k0 >> 3;
  const int cs = (c & ~7) | ((c ^ r) & 7);       // XOR-swizzle 16B chunks in 128B blocks
  u16* dst = Xg + (size_t)r*Hd + cs*8 + (k0 & 7);
  const int t = gtok[r];
  u16x4 o;
  if (t < 0){
    o[0]=0;o[1]=0;o[2]=0;o[3]=0;
  } else {
    const float m = mu[t], s = rstd[t];
    const f32x4 xv = *(const f32x4*)(x   + (size_t)t*Hd + k0);
    const f32x4 wv = *(const f32x4*)(lnw + (size_t)e*Hd + k0);
    const f32x4 bv = *(const f32x4*)(lnb + (size_t)e*Hd + k0);
#pragma unroll
    for (int i=0;i<4;i++) o[i] = f2bf((xv[i]-m)*s*wv[i] + bv[i]);
  }
  *(u16x4*)dst = o;
}

// ---------------- weight prepass: [e][K][N] f32 -> [e][N][K] bf16, swizzled --
// f32x4 loads (16 B/lane, G13 sweet spot)
template<int K, int N>
__global__ __launch_bounds__(256) void k_wt(const float* __restrict__ W,
                                            u16* __restrict__ Wt)
{
  const int e = blockIdx.z, kb = blockIdx.x*64, nb = blockIdx.y*64;
  __shared__ u16 T[64*66];
  const int tid = threadIdx.x;
#pragma unroll
  for (int j=0;j<4;j++){
    const int idx = j*256 + tid;          // 1024 f32x4 quads
    const int k = idx >> 4;               // 0..63
    const int n = (idx & 15) << 2;        // 0..60, step 4
    const f32x4 v = *(const f32x4*)(W + ((size_t)e*K + kb + k)*N + nb + n);
    T[(n+0)*66 + k] = f2bf(v[0]);
    T[(n+1)*66 + k] = f2bf(v[1]);
    T[(n+2)*66 + k] = f2bf(v[2]);
    T[(n+3)*66 + k] = f2bf(v[3]);
  }
  __syncthreads();
  const int nl = tid >> 2;
  const int gn = nb + nl;
  u16* dstrow = Wt + ((size_t)e*N + gn)*K;
#pragma unroll
  for (int cc=0; cc<2; ++cc){
    const int c = ((tid & 3) << 1) + cc;  // local chunk 0..7
    u32x4 v;
#pragma unroll
    for (int i=0;i<4;i++) v[i] = *(const u32*)&T[nl*66 + c*8 + i*2];
    const int cabs = (kb >> 3) + c;
    const int cs = (cabs & ~7) | ((cabs ^ gn) & 7);
    *(u32x4*)(dstrow + cs*8) = v;
  }
}

// ---------------- grouped GEMM: 128x128, BK=64, 4 waves, REG-STAGED ----------
// R6 schedule verbatim (best measured: 177us/GEMM): single prefetch reg set,
// single LDS buffer, 2 barriers per K-tile. Flat global-tile grid: blockIdx.y
// indexes REAL 128-row tiles (segments 128-aligned) -> zero empty blocks.
template<int KD, int ND, bool FC1, int KSPL>
__global__ __launch_bounds__(256, 3) void k_gemm8(
    const u16* __restrict__ A, const u16* __restrict__ Bt,
    const float* __restrict__ bias, const int* __restrict__ meta,
    const int* __restrict__ gtok, const float* __restrict__ gw,
    u16* __restrict__ Mid, float* __restrict__ out)
{
  constexpr int NT = ND/128;
  const int nt = blockIdx.x % NT;
  const int kc = blockIdx.x / NT;
  const int gt = blockIdx.y;

  __shared__ int ps[9];
  const int tid = threadIdx.x;
  if (tid < 9) ps[tid] = meta[tid];
  __syncthreads();
  const int row0 = gt*128;
  if (row0 >= ps[8]) return;
  int e = 0;
#pragma unroll
  for (int i=1;i<8;i++) if (row0 >= ps[i]) e = i;

  __shared__ __attribute__((aligned(16))) u16 As[128*64];  // 16 KB
  __shared__ __attribute__((aligned(16))) u16 Bs[128*64];  // 16 KB

  const int lane = tid & 63, wid = tid >> 6;
  const int wm = wid >> 1, wn = wid & 1;
  const int l15 = lane & 15, l4 = lane >> 4;

  f32x4 acc[4][4] = {};

  const u16* Ap  = A  + (size_t)row0*KD;
  const u16* Btp = Bt + ((size_t)e*ND + (size_t)nt*128)*KD;

  const int ktn = KD/64/KSPL;
  const int kt0 = kc * ktn;
  const int kt1 = kt0 + ktn;

  const int trow = tid >> 3;
  const int tch  = tid & 7;

  u32x4 ra[4], rb[4];

  // prologue: stage tile kt0
#pragma unroll
  for (int j=0;j<4;j++){
    const size_t off = (size_t)(j*32 + trow)*KD + (size_t)kt0*64 + tch*8;
    ra[j] = *(const u32x4*)(Ap + off);
    rb[j] = *(const u32x4*)(Btp + off);
  }
#pragma unroll
  for (int j=0;j<4;j++){
    *(u32x4*)(&As[(j*256+tid)*8]) = ra[j];
    *(u32x4*)(&Bs[(j*256+tid)*8]) = rb[j];
  }
  __syncthreads();

#pragma unroll 1
  for (int kt=kt0; kt<kt1; ++kt){
    // issue next tile's loads early (hide under compute)
    if (kt+1 < kt1){
#pragma unroll
      for (int j=0;j<4;j++){
        const size_t off = (size_t)(j*32 + trow)*KD + (size_t)(kt+1)*64 + tch*8;
        ra[j] = *(const u32x4*)(Ap + off);
        rb[j] = *(const u32x4*)(Btp + off);
      }
    }
    // compute current tile from LDS
#pragma unroll
    for (int ks=0; ks<2; ++ks){
      bf16x8 af[4], bfv[4];
#pragma unroll
      for (int mi=0;mi<4;mi++){
        const int r  = wm*64 + mi*16 + l15;
        const int cb = (ks*4 + l4) ^ (r & 7);
        af[mi] = __builtin_bit_cast(bf16x8, *(const u16x8*)(&As[r*64 + cb*8]));
      }
#pragma unroll
      for (int ni=0;ni<4;ni++){
        const int n  = wn*64 + ni*16 + l15;
        const int cb = (ks*4 + l4) ^ (n & 7);
        bfv[ni] = __builtin_bit_cast(bf16x8, *(const u16x8*)(&Bs[n*64 + cb*8]));
      }
#pragma unroll
      for (int mi=0;mi<4;mi++)
#pragma unroll
        for (int ni=0;ni<4;ni++)
          acc[mi][ni] = __builtin_amdgcn_mfma_f32_16x16x32_bf16(af[mi], bfv[ni], acc[mi][ni], 0, 0, 0);
    }
    __syncthreads();                 // all LDS reads done
    if (kt+1 < kt1){
#pragma unroll
      for (int j=0;j<4;j++){
        *(u32x4*)(&As[(j*256+tid)*8]) = ra[j];
        *(u32x4*)(&Bs[(j*256+tid)*8]) = rb[j];
      }
      __syncthreads();               // staged tile visible
    }
  }

  if (FC1){
#pragma unroll
    for (int mi=0;mi<4;mi++){
      const int grow = row0 + wm*64 + mi*16 + l4*4;
#pragma unroll
      for (int ni=0;ni<4;ni++){
        const int col = nt*128 + wn*64 + ni*16 + l15;
        const float bv = bias[e*ND + col];
#pragma unroll
        for (int j=0;j<4;j++){
          const float v = acc[mi][ni][j] + bv;
          // gelu(tanh) = v * sigmoid(2*0.79788456*(v + 0.044715 v^3))
          const float z = 0.7978845608028654f * (v + 0.044715f*v*v*v);
          const float g = v / (1.f + __expf(-2.f*z));
          const int gr = grow + j;
          const int cc = col >> 3;
          const int ccs = (cc & ~7) | ((cc ^ gr) & 7);
          Mid[(size_t)gr*Fd + ccs*8 + (col&7)] = f2bf(g);
        }
      }
    }
  } else {
#pragma unroll
    for (int mi=0;mi<4;mi++){
#pragma unroll
      for (int j=0;j<4;j++){
        const int gr = row0 + wm*64 + mi*16 + l4*4 + j;
        const int t = gtok[gr];
        if (t < 0) continue;
        const float wt = gw[gr];
#pragma unroll
        for (int ni=0;ni<4;ni++){
          const int col = nt*128 + wn*64 + ni*16 + l15;
          const float bv = (kc == 0) ? bias[e*ND + col] : 0.f;
          const float v = acc[mi][ni][j] + bv;
          atomicAdd(out + (size_t)t*Hd + col, v*wt);
        }
      }
    }
  }
}

// ---------------- fallback GEMM (ws too small): 128x128, in-kernel B convert --
template<int KD, int ND, bool FC1, int KSPL>
__global__ __launch_bounds__(256) void k_gemm_fb(
    const u16* __restrict__ A, const float* __restrict__ B,
    const float* __restrict__ bias, const int* __restrict__ meta,
    const int* __restrict__ gtok, const float* __restrict__ gw,
    u16* __restrict__ Mid, float* __restrict__ out)
{
  const int e = blockIdx.z, mt = blockIdx.y;
  const int nt = blockIdx.x % (ND/128);
  const int kc = blockIdx.x / (ND/128);
  const int p0 = meta[e];
  const int pcnt = meta[e+1] - p0;
  if (mt*128 >= pcnt) return;
  const int row0 = p0 + mt*128;

  __shared__ __attribute__((aligned(16))) u16 As1[128*64];
  __shared__ __attribute__((aligned(16))) u16 Bs1[128*64];

  const int tid = threadIdx.x;
  const int lane = tid & 63, wid = tid >> 6;
  const int wm = wid >> 1, wn = wid & 1;
  const int l15 = lane & 15, l4 = lane >> 4;

  f32x4 acc[4][4] = {};

  const int sbn = (tid & 63) << 1;
  const int skg = tid >> 6;
  const float* Bp = B + (size_t)e*KD*ND + (size_t)nt*128;
  const int kt0 = kc * (KD/64/KSPL);
  const int kt1 = kt0 + (KD/64/KSPL);

  for (int kt=kt0; kt<kt1; ++kt){
    __syncthreads();
#pragma unroll
    for (int j=0;j<4;j++){
      const int cidx = j*256 + tid;
      gll16(A + (size_t)(row0 + (cidx>>3))*KD + kt*64 + (cidx&7)*8, &As1[cidx*8]);
    }
    {
      const float* bsrc = Bp + (size_t)(kt*64 + skg*16)*ND + sbn;
      u32 ra[8], rb[8];
#pragma unroll
      for (int i=0;i<16;i++){
        const f32x2 v = *(const f32x2*)(bsrc + (size_t)i*ND);
        const u32 lo = f2bf(v[0]), hi = f2bf(v[1]);
        if (i & 1){ ra[i>>1] |= lo<<16; rb[i>>1] |= hi<<16; }
        else      { ra[i>>1]  = lo;     rb[i>>1]  = hi;     }
      }
#pragma unroll
      for (int cl=0; cl<2; ++cl){
        const int cb = skg*2 + cl;
        const u32x4 va = { ra[cl*4], ra[cl*4+1], ra[cl*4+2], ra[cl*4+3] };
        const u32x4 vb = { rb[cl*4], rb[cl*4+1], rb[cl*4+2], rb[cl*4+3] };
        *(u32x4*)(&Bs1[(size_t)sbn    *64 + (cb ^ ( sbn   &7))*8]) = va;
        *(u32x4*)(&Bs1[(size_t)(sbn+1)*64 + (cb ^ ((sbn+1)&7))*8]) = vb;
      }
    }
    __syncthreads();
#pragma unroll
    for (int ks=0; ks<2; ++ks){
      bf16x8 af[4], bfv[4];
#pragma unroll
      for (int mi=0;mi<4;mi++){
        const int r  = wm*64 + mi*16 + l15;
        const int cb = (ks*4 + l4) ^ (r & 7);
        af[mi] = __builtin_bit_cast(bf16x8, *(const u16x8*)(&As1[r*64 + cb*8]));
      }
#pragma unroll
      for (int ni=0;ni<4;ni++){
        const int n  = wn*64 + ni*16 + l15;
        const int cb = (ks*4 + l4) ^ (n & 7);
        bfv[ni] = __builtin_bit_cast(bf16x8, *(const u16x8*)(&Bs1[n*64 + cb*8]));
      }
#pragma unroll
      for (int mi=0;mi<4;mi++)
#pragma unroll
        for (int ni=0;ni<4;ni++)
          acc[mi][ni] = __builtin_amdgcn_mfma_f32_16x16x32_bf16(af[mi], bfv[ni], acc[mi][ni], 0, 0, 0);
    }
  }

  if (FC1){
#pragma unroll
    for (int mi=0;mi<4;mi++){
      const int grow = row0 + wm*64 + mi*16 + l4*4;
#pragma unroll
      for (int ni=0;ni<4;ni++){
        const int col = nt*128 + wn*64 + ni*16 + l15;
        const float bv = bias[e*ND + col];
#pragma unroll
        for (int j=0;j<4;j++){
          const float v = acc[mi][ni][j] + bv;
          const float z = 0.7978845608028654f * (v + 0.044715f*v*v*v);
          const float g = v / (1.f + __expf(-2.f*z));
          const int gr = grow + j;
          const int cc = col >> 3;
          const int ccs = (cc & ~7) | ((cc ^ gr) & 7);
          Mid[(size_t)gr*Fd + ccs*8 + (col&7)] = f2bf(g);
        }
      }
    }
  } else {
#pragma unroll
    for (int mi=0;mi<4;mi++){
#pragma unroll
      for (int j=0;j<4;j++){
        const int gr = row0 + wm*64 + mi*16 + l4*4 + j;
        const int t = gtok[gr];
        if (t < 0) continue;
        const float wt = gw[gr];
#pragma unroll
        for (int ni=0;ni<4;ni++){
          const int col = nt*128 + wn*64 + ni*16 + l15;
          const float bv = (kc == 0) ? bias[e*ND + col] : 0.f;
          const float v = acc[mi][ni][j] + bv;
          atomicAdd(out + (size_t)t*Hd + col, v*wt);
        }
      }
    }
  }
}

// ---------------- launcher ---------------------------------------------------
extern "C" void kernel_launch(void* const* d_in, const int* in_sizes, int n_in,
                              void* d_out, int out_size, void* d_ws, size_t ws_size,
                              hipStream_t stream)
{
  const float* x     = (const float*)d_in[0];
  const float* Wg    = (const float*)d_in[1];
  const float* alpha = (const float*)d_in[2];
  const float* lnw   = (const float*)d_in[3];
  const float* lnb   = (const float*)d_in[4];
  const float* w1    = (const float*)d_in[5];
  const float* b1    = (const float*)d_in[6];
  const float* w2    = (const float*)d_in[7];
  const float* b2    = (const float*)d_in[8];
  float* out = (float*)d_out;
  char* ws = (char*)d_ws;

  float* mu    = (float*)(ws + 0);
  float* rstd  = (float*)(ws + (16<<10));
  int*   tok_e = (int*)  (ws + (32<<10));
  float* tok_w = (float*)(ws + (64<<10));
  int*   meta  = (int*)  (ws + (96<<10));
  int*   cnt   = (int*)  (ws + (97<<10));     // 16 chunks x 8 experts
  int*   base  = (int*)  (ws + (98<<10));     // 16 x 8 scatter offsets
  int*   gtok  = (int*)  (ws + (100<<10));
  float* gw    = (float*)(ws + (144<<10));
  u16*   Xg    = (u16*)  (ws + (192<<10));
  const size_t xg_b   = 2*(size_t)ROWS_CAP*Hd;   // 18.9 MB
  const size_t mid_b  = 2*(size_t)ROWS_CAP*Fd;   // 75.5 MB
  const size_t wt_b   = 2*(size_t)Ed*Hd*Fd;      // 67.1 MB each
  u16*   Amid  = (u16*)  (ws + (192<<10) + xg_b);
  u16*   Wt2   = (u16*)  (ws + (192<<10) + xg_b + mid_b);
  u16*   Wt1   = (u16*)  (ws + (192<<10) + xg_b + mid_b + wt_b);

  const size_t base_need = (192<<10) + xg_b + mid_b;
  if (ws_size < base_need){
    fprintf(stderr, "kernel_launch: ws_size %zu < needed %zu\n", ws_size, base_need);
    return;
  }
  const bool cv2 = ws_size >= base_need + wt_b;        // convert w2
  const bool cv1 = ws_size >= base_need + 2*wt_b;      // convert w1 too

  hipMemsetAsync(d_out, 0, (size_t)out_size*sizeof(float), stream);
  hipMemsetAsync(gtok, 0xFF, (size_t)ROWS_CAP*sizeof(int), stream);   // -1 pads
  hipMemsetAsync(gw,   0x00, (size_t)ROWS_CAP*sizeof(float), stream);

  if (cv2) k_wt<Fd, Hd><<<dim3(Fd/64, Hd/64, Ed), 256, 0, stream>>>(w2, Wt2);
  if (cv1) k_wt<Hd, Fd><<<dim3(Hd/64, Fd/64, Ed), 256, 0, stream>>>(w1, Wt1);
  k_gate   <<<Td, 256, 0, stream>>>(x, Wg, alpha, mu, rstd, tok_e, tok_w);
  k_hist   <<<Td/256, 256, 0, stream>>>(tok_e, cnt);
  k_scan   <<<1, 64, 0, stream>>>(cnt, meta, base);
  k_scatter<<<Td/256, 256, 0, stream>>>(tok_e, tok_w, base, gtok, gw);
  k_gather <<<ROWS_CAP, 256, 0, stream>>>(x, lnw, lnb, mu, rstd, meta, gtok, Xg);

  if (cv1)
    k_gemm8<Hd, Fd, true, 1><<<dim3(Fd/128, ROWS_CAP/128), 256, 0, stream>>>(
        Xg, Wt1, b1, meta, gtok, gw, Amid, nullptr);
  else
    k_gemm_fb<Hd, Fd, true, 1><<<dim3(Fd/128, ROWS_CAP/128, Ed), 256, 0, stream>>>(
        Xg, w1, b1, meta, gtok, gw, Amid, nullptr);

  if (cv2)
    k_gemm8<Fd, Hd, false, 2><<<dim3((Hd/128)*2, ROWS_CAP/128), 256, 0, stream>>>(
        Amid, Wt2, b2, meta, gtok, gw, nullptr, out);
  else
    k_gemm_fb<Fd, Hd, false, 2><<<dim3((Hd/128)*2, ROWS_CAP/128, Ed), 256, 0, stream>>>(
        Amid, w2, b2, meta, gtok, gw, nullptr, out);
}